// Round 1
// baseline (717.865 us; speedup 1.0000x reference)
//
#include <hip/hip_runtime.h>
#include <stdint.h>

#define B_N 16384
#define D_N 1024
#define H_N 4096

typedef int i32x4 __attribute__((ext_vector_type(4)));
typedef int i32x8 __attribute__((ext_vector_type(8)));
typedef float f32x4 __attribute__((ext_vector_type(4)));

__device__ __forceinline__ void gload16(const void* g, void* l) {
  __builtin_amdgcn_global_load_lds((const __attribute__((address_space(1))) void*)g,
                                   (__attribute__((address_space(3))) void*)l,
                                   16, 0, 0);
}

__device__ __forceinline__ unsigned char f2fp8(float v) {
  return (unsigned char)(__builtin_amdgcn_cvt_pk_fp8_f32(v, v, 0, false) & 0xFF);
}

// within-64-block H permutation used for Dh stores / W2T K-index:
// u = j*16+lm  ->  lm*4+j
__device__ __forceinline__ int perm_h(int h) {
  return (h & ~63) | ((h & 15) << 2) | ((h >> 4) & 3);
}

// ================= prep (single dispatch): pack X, transpose W1/W2 =========
__device__ __forceinline__ void transpose_tile(
    const float* __restrict__ in, unsigned char* __restrict__ out,
    int R, int C, float scale, float* __restrict__ w3, int pci,
    int i0, int j0, int tx, int ty, bool permute) {
  __shared__ float tile[32][33];
#pragma unroll
  for (int r = 0; r < 32; r += 8) {
    int i = i0 + ty + r;
    int j = j0 + tx;
    float v = in[(size_t)i * C + j];
    tile[ty + r][tx] = v;
    if (w3 != nullptr && i == pci) w3[j] = v;
  }
  __syncthreads();
#pragma unroll
  for (int r = 0; r < 32; r += 8) {
    int jo = j0 + ty + r;
    int io = i0 + tx;
    int ioo = permute ? perm_h(io) : io;
    out[(size_t)jo * R + ioo] = f2fp8(tile[tx][ty + r] * scale);
  }
}

__global__ __launch_bounds__(256) void prep_kernel(
    const float4* __restrict__ X4, int* __restrict__ Xb,
    float* __restrict__ s,
    const float* __restrict__ W1, unsigned char* __restrict__ W1T, float* __restrict__ w3,
    const float* __restrict__ W2, unsigned char* __restrict__ W2T,
    const int* __restrict__ pci_p, float* __restrict__ out0) {
  int b = blockIdx.x;
  int tid = threadIdx.x;
  int pci = *pci_p;
  if (b == 0 && tid == 0) out0[0] = 0.0f;   // zero the output accumulator
  if (b < 8192) {
    int i = (b * 256 + tid) * 2;
#pragma unroll
    for (int u = 0; u < 2; u++) {
      float4 v = X4[i + u];
      int p = __builtin_amdgcn_cvt_pk_fp8_f32(v.x, v.y, 0, false);
      p = __builtin_amdgcn_cvt_pk_fp8_f32(v.z, v.w, p, true);
      Xb[i + u] = p;
      if (((i + u) & (D_N / 4 - 1)) == (pci >> 2)) {
        int row = (i + u) >> 8;
        float c;
        switch (pci & 3) {
          case 0:  c = v.x; break;
          case 1:  c = v.y; break;
          case 2:  c = v.z; break;
          default: c = v.w; break;
        }
        s[row] = 1.0f - 2.0f * c;
      }
    }
  } else if (b < 12288) {
    // W1 (D_N x H_N) -> W1T[h][d] = W1[d][h]*16 ; rows h NOT permuted
    int id = b - 8192;
    transpose_tile(W1, W1T, D_N, H_N, 16.0f, w3, pci,
                   (id >> 7) * 32, (id & 127) * 32, tid & 31, tid >> 5, false);
  } else {
    // W2 (H_N x D_N) -> W2T[d][perm(h)] = W2[h][d]*64 ; K(=H) permuted
    int id = b - 12288;
    transpose_tile(W2, W2T, H_N, D_N, 64.0f, nullptr, -1,
                   (id >> 5) * 32, (id & 31) * 32, tid & 31, tid >> 5, true);
  }
}

// ============= 8-phase MX-fp8 mainloop: 256x256 tile, 8 waves ==============
// T3+T4+T5 stack: double-buffered 128 KiB LDS, per-phase {ds_read frags ||
// issue global_load_lds -> s_barrier -> setprio(1) MFMA x8 setprio(0) ->
// s_barrier}, counted vmcnt (4/2, never 0 in steady state) so prefetch loads
// stay in flight across barriers. Staging chunk order per tile:
// B0,B1 | B2,B3 | A0,A2 | A1,A3  (A rows 64..127/192..255 are first consumed
// at phase 2 of the NEXT tile -> they may arrive latest).
// LDS XOR-swizzle via pre-swizzled global source (linear gload_lds dest);
// reader XORs back. Raw s_barrier (no vmcnt drain) + compiler fences.
template <int KTOT>
__device__ __forceinline__ void mx8_mainloop(
    const unsigned char* __restrict__ A, const unsigned char* __restrict__ B,
    int m0, int n0, int sa, int sb,
    unsigned char* __restrict__ As, unsigned char* __restrict__ Bs,
    f32x4 (&acc)[8][4]) {
  static_assert(KTOT % 128 == 0, "KTOT must be a multiple of 128");
  const int tid = threadIdx.x;
  const int lane = tid & 63;
  const int wave = tid >> 6;
  const int wm = (wave >> 2) * 128;   // 2 waves in M
  const int wn = (wave & 3) * 64;     // 4 waves in N
  const int lm = lane & 15;
  const int quad = lane >> 4;

  const int srow = tid >> 3;          // 0..63: row within a 64-row chunk
  const int sg = tid & 7;             // 16B granule
  const unsigned char* Ag = A + (size_t)(m0 + srow) * KTOT + ((sg ^ (srow & 7)) * 16);
  const unsigned char* Bg = B + (size_t)(n0 + srow) * KTOT + ((sg ^ (srow & 7)) * 16);
  unsigned char* AsW = As + tid * 16;
  unsigned char* BsW = Bs + tid * 16;

#define STGA(c_, k_, p_) gload16(Ag + (k_) + (c_) * 64 * KTOT, AsW + (p_) * 32768 + (c_) * 8192)
#define STGB(c_, k_, p_) gload16(Bg + (k_) + (c_) * 64 * KTOT, BsW + (p_) * 32768 + (c_) * 8192)
#define LDF(d_, base_, r_) { \
    const int rr_ = (r_); \
    const int e_ = rr_ & 7; \
    const unsigned char* pp_ = (base_) + rr_ * 128; \
    i32x4 lo_ = *(const i32x4*)(pp_ + (((2 * quad) ^ e_) * 16)); \
    i32x4 hi_ = *(const i32x4*)(pp_ + (((2 * quad + 1) ^ e_) * 16)); \
    d_ = __builtin_shufflevector(lo_, hi_, 0, 1, 2, 3, 4, 5, 6, 7); }
#define MF(a_, b_, c_) \
    __builtin_amdgcn_mfma_scale_f32_16x16x128_f8f6f4((a_), (b_), (c_), 0, 0, 0, sa, 0, sb)
#define FENCE() asm volatile("" ::: "memory")
#define BARR() { FENCE(); __builtin_amdgcn_s_barrier(); FENCE(); }
#define MM8(i0_, i1_, aA_, aB_) { \
    __builtin_amdgcn_s_setprio(1); \
    acc[i0_][0] = MF(aA_, b0, acc[i0_][0]); \
    acc[i0_][1] = MF(aA_, b1, acc[i0_][1]); \
    acc[i0_][2] = MF(aA_, b2, acc[i0_][2]); \
    acc[i0_][3] = MF(aA_, b3, acc[i0_][3]); \
    acc[i1_][0] = MF(aB_, b0, acc[i1_][0]); \
    acc[i1_][1] = MF(aB_, b1, acc[i1_][1]); \
    acc[i1_][2] = MF(aB_, b2, acc[i1_][2]); \
    acc[i1_][3] = MF(aB_, b3, acc[i1_][3]); \
    __builtin_amdgcn_s_setprio(0); }

  // Prologue: tile 0, FIFO order B0..B3,A0,A2 then A1,A3; first 6 must land.
  STGB(0, 0, 0); STGB(1, 0, 0); STGB(2, 0, 0); STGB(3, 0, 0);
  STGA(0, 0, 0); STGA(2, 0, 0);
  STGA(1, 0, 0); STGA(3, 0, 0);
  asm volatile("s_waitcnt vmcnt(2)" ::: "memory");
  BARR();

  const int NT = KTOT / 128;
#pragma unroll 2
  for (int t = 0; t < NT; ++t) {
    const unsigned char* Ar = As + (t & 1) * 32768;
    const unsigned char* Br = Bs + (t & 1) * 32768;
    const int pq = (t & 1) ^ 1;
    const int k1 = (t + 1) * 128;
    const bool pf = (t + 1 < NT);

    i32x8 b0, b1, b2, b3, av0, av1;
    // ---- phase 0: all 4 b-frags (held across tile) + a0,a1
    LDF(b0, Br, wn + lm);
    LDF(b1, Br, wn + 16 + lm);
    LDF(b2, Br, wn + 32 + lm);
    LDF(b3, Br, wn + 48 + lm);
    LDF(av0, Ar, wm + lm);
    LDF(av1, Ar, wm + 16 + lm);
    if (pf) { STGB(0, k1, pq); STGB(1, k1, pq); }
    BARR();
    MM8(0, 1, av0, av1);
    BARR();

    // ---- phase 1
    LDF(av0, Ar, wm + 32 + lm);
    LDF(av1, Ar, wm + 48 + lm);
    if (pf) { STGB(2, k1, pq); STGB(3, k1, pq); }
    BARR();
    MM8(2, 3, av0, av1);
    // Need this tile's A1,A3 (issued at t-1 phase 3) before phase-2 reads.
    // Outstanding FIFO: [A1,A3, B0',B1',B2',B3'] -> vmcnt(4). Tail: drain.
    if (pf) { asm volatile("s_waitcnt vmcnt(4)" ::: "memory"); }
    else    { asm volatile("s_waitcnt vmcnt(0)" ::: "memory"); }
    BARR();

    // ---- phase 2: rows 64..95 / 192..223 (chunks A1/A3, just waited)
    LDF(av0, Ar, wm + 64 + lm);
    LDF(av1, Ar, wm + 80 + lm);
    if (pf) { STGA(0, k1, pq); STGA(2, k1, pq); }
    BARR();
    MM8(4, 5, av0, av1);
    BARR();

    // ---- phase 3
    LDF(av0, Ar, wm + 96 + lm);
    LDF(av1, Ar, wm + 112 + lm);
    if (pf) { STGA(1, k1, pq); STGA(3, k1, pq); }
    BARR();
    MM8(6, 7, av0, av1);
    // Next tile needs B0'..B3',A0',A2' (first 6 of 8 outstanding) -> vmcnt(2);
    // A1',A3' stay in flight across the boundary.
    if (pf) { asm volatile("s_waitcnt vmcnt(2)" ::: "memory"); }
    BARR();
  }
#undef STGA
#undef STGB
#undef LDF
#undef MF
#undef FENCE
#undef BARR
#undef MM8
}

// ---- GEMM1: Z = X @ W1, epilogue Dh = 64*(tanh(z)-tanh(z+s*w3)) -> fp8 ----
// 1024 blocks (64 m x 16 n), 512 thr, 1 block/CU, 4 exact generations.
// XCD map: x = l&7 owns m-panels x*8..x*8+7 forever (2 MB Xb L2-pinned);
// n advances across generations (1 MB W1T slice live per gen).
__global__ __launch_bounds__(512, 2) void gemm1_dh(
    const unsigned char* __restrict__ Xb,    // B_N x D_N fp8 (x1)
    const unsigned char* __restrict__ W1T,   // H_N x D_N fp8 (x16)
    const float* __restrict__ b1,
    const float* __restrict__ w3,            // H_N : W1[pci][h] f32
    const float* __restrict__ s,             // B_N : 1-2*col
    unsigned int* __restrict__ Dh4) {        // B_N x H_N fp8 (x64), perm'd cols
  __shared__ alignas(16) unsigned char As[65536];
  __shared__ alignas(16) unsigned char Bs[65536];
  const int l = blockIdx.x;
  const int x = l & 7;
  const int k = l >> 3;                      // 0..127 per XCD
  const int m0 = (x * 8 + (k & 7)) * 256;
  const int n0 = (k >> 3) * 256;

  f32x4 acc[8][4] = {};
  mx8_mainloop<D_N>(Xb, W1T, m0, n0, 127, 123, As, Bs, acc);  // 2^0 * 2^-4

  const int tid = threadIdx.x;
  const int lane = tid & 63;
  const int wave = tid >> 6;
  const int wm = (wave >> 2) * 128;
  const int wn = (wave & 3) * 64;
  const int lm = lane & 15;
  const int quad = lane >> 4;

  float ewp[4], ewm[4], nump[4], numm[4], b1v[4];
#pragma unroll
  for (int j = 0; j < 4; j++) {
    int gh = n0 + wn + j * 16 + lm;
    float w = w3[gh];
    float ep = __expf(2.0f * w);
    float em = __expf(-2.0f * w);
    ewp[j] = ep; ewm[j] = em;
    nump[j] = 128.0f * (1.0f - ep);
    numm[j] = 128.0f * (1.0f - em);
    b1v[j] = b1[gh];
  }
  const size_t coloff = (size_t)((n0 + wn) >> 2) + lm;
#pragma unroll
  for (int i = 0; i < 8; i++) {
#pragma unroll
    for (int r = 0; r < 4; r++) {
      int gb = m0 + wm + i * 16 + quad * 4 + r;
      bool sp = s[gb] > 0.0f;
      float o[4];
#pragma unroll
      for (int j = 0; j < 4; j++) {
        float ews = sp ? ewp[j] : ewm[j];
        float num = sp ? nump[j] : numm[j];
        float z = fminf(acc[i][j][r] + b1v[j], 12.0f);
        float E = __expf(2.0f * z);
        float den = (E * ews + 1.0f) * (E + 1.0f);
        o[j] = (E * num) * __builtin_amdgcn_rcpf(den);  // 64*dh
      }
      int p = __builtin_amdgcn_cvt_pk_fp8_f32(o[0], o[1], 0, false);
      p = __builtin_amdgcn_cvt_pk_fp8_f32(o[2], o[3], p, true);
      Dh4[(size_t)gb * (H_N / 4) + coloff] = (unsigned int)p;
    }
  }
}

// ---- GEMM2: Y = Dh @ W2, epilogue mean-scaled sum|Y| -> atomic d_out ----
// 256 blocks (64 m x 4 n) = ONE exact generation at 1 block/CU; same
// m-panel<->XCD map as gemm1 so Dh re-reads hit that XCD's L2.
__global__ __launch_bounds__(512, 2) void gemm2_abs(
    const unsigned char* __restrict__ Dh,    // B_N x H_N fp8 (x64), perm'd K
    const unsigned char* __restrict__ W2T,   // D_N x H_N fp8 (x64), perm'd K
    float* __restrict__ out) {
  __shared__ alignas(16) unsigned char As[65536];
  __shared__ alignas(16) unsigned char Bs[65536];
  __shared__ float wsum[8];
  const int l = blockIdx.x;
  const int x = l & 7;
  const int k = l >> 3;                      // 0..31 per XCD
  const int m0 = (x * 8 + (k & 7)) * 256;
  const int n0 = (k >> 3) * 256;

  f32x4 acc[8][4] = {};
  mx8_mainloop<H_N>(Dh, W2T, m0, n0, 121, 121, As, Bs, acc);  // 2^-6 * 2^-6

  const int tid = threadIdx.x;
  const int lane = tid & 63;
  const int wave = tid >> 6;

  float t = 0.0f;
#pragma unroll
  for (int i = 0; i < 8; i++)
#pragma unroll
    for (int j = 0; j < 4; j++)
#pragma unroll
      for (int r = 0; r < 4; r++)
        t += fabsf(acc[i][j][r]);

#pragma unroll
  for (int off2 = 32; off2 > 0; off2 >>= 1)
    t += __shfl_down(t, off2, 64);
  if (lane == 0) wsum[wave] = t;
  __syncthreads();
  if (tid == 0) {
    float tt = 0.0f;
#pragma unroll
    for (int w = 0; w < 8; w++) tt += wsum[w];
    atomicAdd(out, tt * (1.0f / (float)B_N));
  }
}

extern "C" void kernel_launch(void* const* d_in, const int* in_sizes, int n_in,
                              void* d_out, int out_size, void* d_ws, size_t ws_size,
                              hipStream_t stream) {
  const float* X  = (const float*)d_in[0];
  const float* W1 = (const float*)d_in[1];
  const float* b1 = (const float*)d_in[2];
  const float* W2 = (const float*)d_in[3];
  // d_in[4] = b2 : cancels in the difference
  const int* pci  = (const int*)d_in[5];

  char* ws = (char*)d_ws;
  size_t off = 0;
  unsigned char* Xb  = (unsigned char*)(ws + off); off += (size_t)B_N * D_N;
  unsigned char* W1T = (unsigned char*)(ws + off); off += (size_t)H_N * D_N;
  unsigned char* W2T = (unsigned char*)(ws + off); off += (size_t)D_N * H_N;
  float* w3  = (float*)(ws + off); off += (size_t)H_N * 4;
  float* s   = (float*)(ws + off); off += (size_t)B_N * 4;
  unsigned char* Dh  = (unsigned char*)(ws + off); off += (size_t)B_N * H_N;
  if (ws_size < off) return;

  prep_kernel<<<16384, 256, 0, stream>>>((const float4*)X, (int*)Xb, s,
                                         W1, W1T, w3, W2, W2T, pci,
                                         (float*)d_out);
  gemm1_dh<<<1024, 512, 0, stream>>>(Xb, W1T, b1, w3, s, (unsigned int*)Dh);
  gemm2_abs<<<256, 512, 0, stream>>>(Dh, W2T, (float*)d_out);
}

// Round 2
// 289.572 us; speedup vs baseline: 2.4791x; 2.4791x over previous
//
#include <hip/hip_runtime.h>
#include <stdint.h>

#define B_N 16384
#define D_N 1024
#define H_N 4096

typedef int i32x4 __attribute__((ext_vector_type(4)));
typedef int i32x8 __attribute__((ext_vector_type(8)));
typedef float f32x4 __attribute__((ext_vector_type(4)));

__device__ __forceinline__ void gload16(const void* g, void* l) {
  __builtin_amdgcn_global_load_lds((const __attribute__((address_space(1))) void*)g,
                                   (__attribute__((address_space(3))) void*)l,
                                   16, 0, 0);
}

__device__ __forceinline__ unsigned char f2fp8(float v) {
  return (unsigned char)(__builtin_amdgcn_cvt_pk_fp8_f32(v, v, 0, false) & 0xFF);
}

// within-64-block H permutation used for Dh stores / W2T K-index:
// u = j*16+lm  ->  lm*4+j
__device__ __forceinline__ int perm_h(int h) {
  return (h & ~63) | ((h & 15) << 2) | ((h >> 4) & 3);
}

// ================= prep (single dispatch): pack X, transpose W1/W2 =========
__device__ __forceinline__ void transpose_tile(
    const float* __restrict__ in, unsigned char* __restrict__ out,
    int R, int C, float scale, float* __restrict__ w3, int pci,
    int i0, int j0, int tx, int ty, bool permute) {
  __shared__ float tile[32][33];
#pragma unroll
  for (int r = 0; r < 32; r += 8) {
    int i = i0 + ty + r;
    int j = j0 + tx;
    float v = in[(size_t)i * C + j];
    tile[ty + r][tx] = v;
    if (w3 != nullptr && i == pci) w3[j] = v;
  }
  __syncthreads();
#pragma unroll
  for (int r = 0; r < 32; r += 8) {
    int jo = j0 + ty + r;
    int io = i0 + tx;
    int ioo = permute ? perm_h(io) : io;
    out[(size_t)jo * R + ioo] = f2fp8(tile[tx][ty + r] * scale);
  }
}

__global__ __launch_bounds__(256) void prep_kernel(
    const float4* __restrict__ X4, int* __restrict__ Xb,
    float* __restrict__ s,
    const float* __restrict__ W1, unsigned char* __restrict__ W1T, float* __restrict__ w3,
    const float* __restrict__ W2, unsigned char* __restrict__ W2T,
    const int* __restrict__ pci_p, float* __restrict__ out0) {
  int b = blockIdx.x;
  int tid = threadIdx.x;
  int pci = *pci_p;
  if (b == 0 && tid == 0) out0[0] = 0.0f;   // zero the output accumulator
  if (b < 8192) {
    int i = (b * 256 + tid) * 2;
#pragma unroll
    for (int u = 0; u < 2; u++) {
      float4 v = X4[i + u];
      int p = __builtin_amdgcn_cvt_pk_fp8_f32(v.x, v.y, 0, false);
      p = __builtin_amdgcn_cvt_pk_fp8_f32(v.z, v.w, p, true);
      Xb[i + u] = p;
      if (((i + u) & (D_N / 4 - 1)) == (pci >> 2)) {
        int row = (i + u) >> 8;
        float c;
        switch (pci & 3) {
          case 0:  c = v.x; break;
          case 1:  c = v.y; break;
          case 2:  c = v.z; break;
          default: c = v.w; break;
        }
        s[row] = 1.0f - 2.0f * c;
      }
    }
  } else if (b < 12288) {
    // W1 (D_N x H_N) -> W1T[h][d] = W1[d][h]*16 ; rows h NOT permuted
    int id = b - 8192;
    transpose_tile(W1, W1T, D_N, H_N, 16.0f, w3, pci,
                   (id >> 7) * 32, (id & 127) * 32, tid & 31, tid >> 5, false);
  } else {
    // W2 (H_N x D_N) -> W2T[d][perm(h)] = W2[h][d]*64 ; K(=H) permuted
    int id = b - 12288;
    transpose_tile(W2, W2T, H_N, D_N, 64.0f, nullptr, -1,
                   (id >> 5) * 32, (id & 31) * 32, tid & 31, tid >> 5, true);
  }
}

// ============= 8-phase MX-fp8 mainloop: 256x256 tile, 8 waves ==============
// Same T3+T4+T5 schedule as round 1 (verified correct), register-pressure
// reworked so arch VGPRs stay far below the 128 cap (256 unified budget at
// 2 waves/SIMD minus 128 AGPR acc):
//  - swizzle XOR is thread-constant (row === lm mod 8 for every fragment), so
//    all ds_reads are 4 held base pointers + compile-time immediate offsets
//  - buffer parity is compile-time (explicit tile pairing, no runtime t&1)
// Staging chunk order per tile: B0,B1 | B2,B3 | A0,A2 | A1,A3 ; counted
// vmcnt(4)/vmcnt(2), never 0 in steady state.
template <int KTOT>
__device__ __forceinline__ void mx8_mainloop(
    const unsigned char* __restrict__ A, const unsigned char* __restrict__ B,
    int m0, int n0, int sa, int sb,
    unsigned char* __restrict__ As, unsigned char* __restrict__ Bs,
    f32x4 (&acc)[8][4]) {
  static_assert(KTOT % 256 == 0, "need an even number of 128-K tiles");
  const int tid = threadIdx.x;
  const int lane = tid & 63;
  const int wave = tid >> 6;
  const int wm = (wave >> 2) * 128;   // 2 waves in M
  const int wn = (wave & 3) * 64;     // 4 waves in N
  const int lm = lane & 15;
  const int quad = lane >> 4;

  // --- staging: pre-swizzled global source, linear LDS dest ---
  const int srow = tid >> 3;          // row within a 64-row chunk
  const int sg = tid & 7;             // 16B granule
  const unsigned char* Ag = A + (size_t)(m0 + srow) * KTOT + ((sg ^ (srow & 7)) * 16);
  const unsigned char* Bg = B + (size_t)(n0 + srow) * KTOT + ((sg ^ (srow & 7)) * 16);
  unsigned char* AsW = As + tid * 16;
  unsigned char* BsW = Bs + tid * 16;

  // --- fragment-read bases: e = lm&7 is thread-constant for ALL fragments ---
  const int e = lm & 7;
  const int lo_off = ((2 * quad) ^ e) * 16;
  const int hi_off = ((2 * quad + 1) ^ e) * 16;
  const unsigned char* Ard_lo = As + (wm + lm) * 128 + lo_off;
  const unsigned char* Ard_hi = As + (wm + lm) * 128 + hi_off;
  const unsigned char* Brd_lo = Bs + (wn + lm) * 128 + lo_off;
  const unsigned char* Brd_hi = Bs + (wn + lm) * 128 + hi_off;

#define STGA(c_, kn_, p_) \
    gload16(Ag + (kn_) + (size_t)(c_) * 64 * KTOT, AsW + (p_) * 32768 + (c_) * 8192)
#define STGB(c_, kn_, p_) \
    gload16(Bg + (kn_) + (size_t)(c_) * 64 * KTOT, BsW + (p_) * 32768 + (c_) * 8192)
#define LDA(d_, i_, P_) { \
    i32x4 lo_ = *(const i32x4*)(Ard_lo + (P_) * 32768 + (i_) * 2048); \
    i32x4 hi_ = *(const i32x4*)(Ard_hi + (P_) * 32768 + (i_) * 2048); \
    d_ = __builtin_shufflevector(lo_, hi_, 0, 1, 2, 3, 4, 5, 6, 7); }
#define LDB(d_, j_, P_) { \
    i32x4 lo_ = *(const i32x4*)(Brd_lo + (P_) * 32768 + (j_) * 2048); \
    i32x4 hi_ = *(const i32x4*)(Brd_hi + (P_) * 32768 + (j_) * 2048); \
    d_ = __builtin_shufflevector(lo_, hi_, 0, 1, 2, 3, 4, 5, 6, 7); }
#define MF(a_, b_, c_) \
    __builtin_amdgcn_mfma_scale_f32_16x16x128_f8f6f4((a_), (b_), (c_), 0, 0, 0, sa, 0, sb)
#define FENCE() asm volatile("" ::: "memory")
#define BARR() { FENCE(); __builtin_amdgcn_s_barrier(); FENCE(); }
#define MM8(i0_, i1_, aA_, aB_) { \
    __builtin_amdgcn_s_setprio(1); \
    acc[i0_][0] = MF(aA_, b0, acc[i0_][0]); \
    acc[i0_][1] = MF(aA_, b1, acc[i0_][1]); \
    acc[i0_][2] = MF(aA_, b2, acc[i0_][2]); \
    acc[i0_][3] = MF(aA_, b3, acc[i0_][3]); \
    acc[i1_][0] = MF(aB_, b0, acc[i1_][0]); \
    acc[i1_][1] = MF(aB_, b1, acc[i1_][1]); \
    acc[i1_][2] = MF(aB_, b2, acc[i1_][2]); \
    acc[i1_][3] = MF(aB_, b3, acc[i1_][3]); \
    __builtin_amdgcn_s_setprio(0); }

// One 128-K tile: reads buffer P_, prefetches K-offset kn_ into buffer 1-P_.
// PF_ is a compile-time bool (last tile: no prefetch, full drain).
#define TILE(P_, kn_, PF_) { \
    i32x8 b0, b1, b2, b3, av0, av1; \
    /* phase 0: 4 b-frags (held all tile) + a0,a1 */ \
    LDB(b0, 0, P_); LDB(b1, 1, P_); LDB(b2, 2, P_); LDB(b3, 3, P_); \
    LDA(av0, 0, P_); LDA(av1, 1, P_); \
    if (PF_) { STGB(0, kn_, 1 - (P_)); STGB(1, kn_, 1 - (P_)); } \
    BARR(); MM8(0, 1, av0, av1); BARR(); \
    /* phase 1 */ \
    LDA(av0, 2, P_); LDA(av1, 3, P_); \
    if (PF_) { STGB(2, kn_, 1 - (P_)); STGB(3, kn_, 1 - (P_)); } \
    BARR(); MM8(2, 3, av0, av1); \
    /* need this tile's A1,A3 (issued last tile ph3) before ph2 reads:    */ \
    /* FIFO outstanding = [A1,A3,B0',B1',B2',B3'] -> vmcnt(4); tail drain */ \
    if (PF_) { asm volatile("s_waitcnt vmcnt(4)" ::: "memory"); } \
    else     { asm volatile("s_waitcnt vmcnt(0)" ::: "memory"); } \
    BARR(); \
    /* phase 2: rows 64..127 / 192..255 (chunks A1/A3, just waited) */ \
    LDA(av0, 4, P_); LDA(av1, 5, P_); \
    if (PF_) { STGA(0, kn_, 1 - (P_)); STGA(2, kn_, 1 - (P_)); } \
    BARR(); MM8(4, 5, av0, av1); BARR(); \
    /* phase 3 */ \
    LDA(av0, 6, P_); LDA(av1, 7, P_); \
    if (PF_) { STGA(1, kn_, 1 - (P_)); STGA(3, kn_, 1 - (P_)); } \
    BARR(); MM8(6, 7, av0, av1); \
    /* next tile needs B0'..B3',A0',A2' -> vmcnt(2); A1',A3' stay in flight */ \
    if (PF_) { asm volatile("s_waitcnt vmcnt(2)" ::: "memory"); } \
    BARR(); }

  // Prologue: stage tile 0, FIFO order B0..B3,A0,A2 then A1,A3.
  STGB(0, 0, 0); STGB(1, 0, 0); STGB(2, 0, 0); STGB(3, 0, 0);
  STGA(0, 0, 0); STGA(2, 0, 0);
  STGA(1, 0, 0); STGA(3, 0, 0);
  asm volatile("s_waitcnt vmcnt(2)" ::: "memory");
  BARR();

  const int NT = KTOT / 128;
  for (int t = 0; t < NT - 2; t += 2) {
    TILE(0, (t + 1) * 128, true);
    TILE(1, (t + 2) * 128, true);
  }
  TILE(0, (NT - 1) * 128, true);
  TILE(1, 0, false);

#undef STGA
#undef STGB
#undef LDA
#undef LDB
#undef MF
#undef FENCE
#undef BARR
#undef MM8
#undef TILE
}

// ---- GEMM1: Z = X @ W1, epilogue Dh = 64*(tanh(z)-tanh(z+s*w3)) -> fp8 ----
// 1024 blocks (64 m x 16 n), 512 thr, 1 block/CU, 4 exact generations.
// XCD map: x = l&7 owns m-panels x*8..x*8+7 forever (2 MB Xb L2-pinned);
// n advances across generations (1 MB W1T slice live per gen).
__global__ __launch_bounds__(512, 2) void gemm1_dh(
    const unsigned char* __restrict__ Xb,    // B_N x D_N fp8 (x1)
    const unsigned char* __restrict__ W1T,   // H_N x D_N fp8 (x16)
    const float* __restrict__ b1,
    const float* __restrict__ w3,            // H_N : W1[pci][h] f32
    const float* __restrict__ s,             // B_N : 1-2*col
    unsigned int* __restrict__ Dh4) {        // B_N x H_N fp8 (x64), perm'd cols
  __shared__ alignas(16) unsigned char As[65536];
  __shared__ alignas(16) unsigned char Bs[65536];
  const int l = blockIdx.x;
  const int x = l & 7;
  const int k = l >> 3;                      // 0..127 per XCD
  const int m0 = (x * 8 + (k & 7)) * 256;
  const int n0 = (k >> 3) * 256;

  f32x4 acc[8][4] = {};
  mx8_mainloop<D_N>(Xb, W1T, m0, n0, 127, 123, As, Bs, acc);  // 2^0 * 2^-4

  const int tid = threadIdx.x;
  const int lane = tid & 63;
  const int wave = tid >> 6;
  const int wm = (wave >> 2) * 128;
  const int wn = (wave & 3) * 64;
  const int lm = lane & 15;
  const int quad = lane >> 4;

  float ewp[4], ewm[4], nump[4], numm[4], b1v[4];
#pragma unroll
  for (int j = 0; j < 4; j++) {
    int gh = n0 + wn + j * 16 + lm;
    float w = w3[gh];
    float ep = __expf(2.0f * w);
    float em = __expf(-2.0f * w);
    ewp[j] = ep; ewm[j] = em;
    nump[j] = 128.0f * (1.0f - ep);
    numm[j] = 128.0f * (1.0f - em);
    b1v[j] = b1[gh];
  }
  const size_t coloff = (size_t)((n0 + wn) >> 2) + lm;
#pragma unroll
  for (int i = 0; i < 8; i++) {
#pragma unroll
    for (int r = 0; r < 4; r++) {
      int gb = m0 + wm + i * 16 + quad * 4 + r;
      bool sp = s[gb] > 0.0f;
      float o[4];
#pragma unroll
      for (int j = 0; j < 4; j++) {
        float ews = sp ? ewp[j] : ewm[j];
        float num = sp ? nump[j] : numm[j];
        float z = fminf(acc[i][j][r] + b1v[j], 12.0f);
        float E = __expf(2.0f * z);
        float den = (E * ews + 1.0f) * (E + 1.0f);
        o[j] = (E * num) * __builtin_amdgcn_rcpf(den);  // 64*dh
      }
      int p = __builtin_amdgcn_cvt_pk_fp8_f32(o[0], o[1], 0, false);
      p = __builtin_amdgcn_cvt_pk_fp8_f32(o[2], o[3], p, true);
      Dh4[(size_t)gb * (H_N / 4) + coloff] = (unsigned int)p;
    }
  }
}

// ---- GEMM2: Y = Dh @ W2, epilogue mean-scaled sum|Y| -> atomic d_out ----
// 256 blocks (64 m x 4 n) = ONE exact generation at 1 block/CU; same
// m-panel<->XCD map as gemm1 so Dh re-reads hit that XCD's L2.
__global__ __launch_bounds__(512, 2) void gemm2_abs(
    const unsigned char* __restrict__ Dh,    // B_N x H_N fp8 (x64), perm'd K
    const unsigned char* __restrict__ W2T,   // D_N x H_N fp8 (x64), perm'd K
    float* __restrict__ out) {
  __shared__ alignas(16) unsigned char As[65536];
  __shared__ alignas(16) unsigned char Bs[65536];
  __shared__ float wsum[8];
  const int l = blockIdx.x;
  const int x = l & 7;
  const int k = l >> 3;                      // 0..31 per XCD
  const int m0 = (x * 8 + (k & 7)) * 256;
  const int n0 = (k >> 3) * 256;

  f32x4 acc[8][4] = {};
  mx8_mainloop<H_N>(Dh, W2T, m0, n0, 121, 121, As, Bs, acc);  // 2^-6 * 2^-6

  const int tid = threadIdx.x;
  const int lane = tid & 63;
  const int wave = tid >> 6;

  float t = 0.0f;
#pragma unroll
  for (int i = 0; i < 8; i++)
#pragma unroll
    for (int j = 0; j < 4; j++)
#pragma unroll
      for (int r = 0; r < 4; r++)
        t += fabsf(acc[i][j][r]);

#pragma unroll
  for (int off2 = 32; off2 > 0; off2 >>= 1)
    t += __shfl_down(t, off2, 64);
  if (lane == 0) wsum[wave] = t;
  __syncthreads();
  if (tid == 0) {
    float tt = 0.0f;
#pragma unroll
    for (int w = 0; w < 8; w++) tt += wsum[w];
    atomicAdd(out, tt * (1.0f / (float)B_N));
  }
}

extern "C" void kernel_launch(void* const* d_in, const int* in_sizes, int n_in,
                              void* d_out, int out_size, void* d_ws, size_t ws_size,
                              hipStream_t stream) {
  const float* X  = (const float*)d_in[0];
  const float* W1 = (const float*)d_in[1];
  const float* b1 = (const float*)d_in[2];
  const float* W2 = (const float*)d_in[3];
  // d_in[4] = b2 : cancels in the difference
  const int* pci  = (const int*)d_in[5];

  char* ws = (char*)d_ws;
  size_t off = 0;
  unsigned char* Xb  = (unsigned char*)(ws + off); off += (size_t)B_N * D_N;
  unsigned char* W1T = (unsigned char*)(ws + off); off += (size_t)H_N * D_N;
  unsigned char* W2T = (unsigned char*)(ws + off); off += (size_t)D_N * H_N;
  float* w3  = (float*)(ws + off); off += (size_t)H_N * 4;
  float* s   = (float*)(ws + off); off += (size_t)B_N * 4;
  unsigned char* Dh  = (unsigned char*)(ws + off); off += (size_t)B_N * H_N;
  if (ws_size < off) return;

  prep_kernel<<<16384, 256, 0, stream>>>((const float4*)X, (int*)Xb, s,
                                         W1, W1T, w3, W2, W2T, pci,
                                         (float*)d_out);
  gemm1_dh<<<1024, 512, 0, stream>>>(Xb, W1T, b1, w3, s, (unsigned int*)Dh);
  gemm2_abs<<<256, 512, 0, stream>>>(Dh, W2T, (float*)d_out);
}

// Round 3
// 275.278 us; speedup vs baseline: 2.6078x; 1.0519x over previous
//
#include <hip/hip_runtime.h>
#include <stdint.h>

#define B_N 16384
#define D_N 1024
#define H_N 4096

typedef int i32x4 __attribute__((ext_vector_type(4)));
typedef int i32x8 __attribute__((ext_vector_type(8)));
typedef float f32x4 __attribute__((ext_vector_type(4)));

__device__ __forceinline__ void gload16(const void* g, void* l) {
  __builtin_amdgcn_global_load_lds((const __attribute__((address_space(1))) void*)g,
                                   (__attribute__((address_space(3))) void*)l,
                                   16, 0, 0);
}

__device__ __forceinline__ unsigned char f2fp8(float v) {
  return (unsigned char)(__builtin_amdgcn_cvt_pk_fp8_f32(v, v, 0, false) & 0xFF);
}

// within-64-block H permutation used for Dh stores / W2T K-index:
// u = j*16+lm  ->  lm*4+j
__device__ __forceinline__ int perm_h(int h) {
  return (h & ~63) | ((h & 15) << 2) | ((h >> 4) & 3);
}

// ================= prep (single dispatch): pack X, transpose W1/W2 =========
__device__ __forceinline__ void transpose_tile(
    const float* __restrict__ in, unsigned char* __restrict__ out,
    int R, int C, float scale, float* __restrict__ w3, int pci,
    int i0, int j0, int tx, int ty, bool permute) {
  __shared__ float tile[32][33];
#pragma unroll
  for (int r = 0; r < 32; r += 8) {
    int i = i0 + ty + r;
    int j = j0 + tx;
    float v = in[(size_t)i * C + j];
    tile[ty + r][tx] = v;
    if (w3 != nullptr && i == pci) w3[j] = v;
  }
  __syncthreads();
#pragma unroll
  for (int r = 0; r < 32; r += 8) {
    int jo = j0 + ty + r;
    int io = i0 + tx;
    int ioo = permute ? perm_h(io) : io;
    out[(size_t)jo * R + ioo] = f2fp8(tile[tx][ty + r] * scale);
  }
}

__global__ __launch_bounds__(256) void prep_kernel(
    const float4* __restrict__ X4, int* __restrict__ Xb,
    float* __restrict__ s,
    const float* __restrict__ W1, unsigned char* __restrict__ W1T, float* __restrict__ w3,
    const float* __restrict__ W2, unsigned char* __restrict__ W2T,
    const int* __restrict__ pci_p, float* __restrict__ out0) {
  int b = blockIdx.x;
  int tid = threadIdx.x;
  int pci = *pci_p;
  if (b == 0 && tid == 0) out0[0] = 0.0f;   // zero the output accumulator
  if (b < 8192) {
    int i = (b * 256 + tid) * 2;
#pragma unroll
    for (int u = 0; u < 2; u++) {
      float4 v = X4[i + u];
      int p = __builtin_amdgcn_cvt_pk_fp8_f32(v.x, v.y, 0, false);
      p = __builtin_amdgcn_cvt_pk_fp8_f32(v.z, v.w, p, true);
      Xb[i + u] = p;
      if (((i + u) & (D_N / 4 - 1)) == (pci >> 2)) {
        int row = (i + u) >> 8;
        float c;
        switch (pci & 3) {
          case 0:  c = v.x; break;
          case 1:  c = v.y; break;
          case 2:  c = v.z; break;
          default: c = v.w; break;
        }
        s[row] = 1.0f - 2.0f * c;
      }
    }
  } else if (b < 12288) {
    // W1 (D_N x H_N) -> W1T[h][d] = W1[d][h]*16 ; rows h NOT permuted
    int id = b - 8192;
    transpose_tile(W1, W1T, D_N, H_N, 16.0f, w3, pci,
                   (id >> 7) * 32, (id & 127) * 32, tid & 31, tid >> 5, false);
  } else {
    // W2 (H_N x D_N) -> W2T[d][perm(h)] = W2[h][d]*64 ; K(=H) permuted
    int id = b - 12288;
    transpose_tile(W2, W2T, H_N, D_N, 64.0f, nullptr, -1,
                   (id >> 5) * 32, (id & 31) * 32, tid & 31, tid >> 5, true);
  }
}

// ========= 4-phase pipelined MX-fp8 mainloop: 256x256 tile, 8 waves ========
// Fragment-level software pipeline: each phase loads the NEXT phase's
// a-fragments (and ph3 preloads the next tile's b-fragments + first a-pair
// from the back buffer), so every MM8 consumes fragments loaded one full
// phase earlier -> no lgkm stall, LDS unit runs concurrently with the MFMA
// pipe. ONE barrier per phase (hazard analysis: all reads of a buffer are
// lgkm-complete before that phase's MM8 issues, which precedes the phase-end
// barrier, which precedes any overwrite of that buffer).
// Staging order per tile t (into buffer 1-P, for tile t+1):
//   ph0: B0',B1' | ph1: B2',B3',A0',A2' | ph2: A1',A3' | ph3: none
// Counted vmcnt, never 0 in steady state:
//   ph0-end vmcnt(2): completes [A1,A3] of THIS tile (leaves B0',B1')
//   ph2-end vmcnt(2): completes B0'..B3',A0',A2'  (leaves A1',A3' in flight)
template <int KTOT>
__device__ __forceinline__ void mx8_mainloop(
    const unsigned char* __restrict__ A, const unsigned char* __restrict__ B,
    int m0, int n0, int sa, int sb,
    unsigned char* __restrict__ As, unsigned char* __restrict__ Bs,
    f32x4 (&acc)[8][4]) {
  static_assert(KTOT % 256 == 0, "need an even number of 128-K tiles");
  const int tid = threadIdx.x;
  const int lane = tid & 63;
  const int wave = tid >> 6;
  const int wm = (wave >> 2) * 128;   // 2 waves in M
  const int wn = (wave & 3) * 64;     // 4 waves in N
  const int lm = lane & 15;
  const int quad = lane >> 4;

  // --- staging: pre-swizzled global source, linear LDS dest ---
  const int srow = tid >> 3;          // row within a 64-row chunk
  const int sg = tid & 7;             // 16B granule
  const unsigned char* Ag = A + (size_t)(m0 + srow) * KTOT + ((sg ^ (srow & 7)) * 16);
  const unsigned char* Bg = B + (size_t)(n0 + srow) * KTOT + ((sg ^ (srow & 7)) * 16);
  unsigned char* AsW = As + tid * 16;
  unsigned char* BsW = Bs + tid * 16;

  // --- fragment-read bases: e = lm&7 is thread-constant for ALL fragments ---
  const int e = lm & 7;
  const int lo_off = ((2 * quad) ^ e) * 16;
  const int hi_off = ((2 * quad + 1) ^ e) * 16;
  const unsigned char* Ard_lo = As + (wm + lm) * 128 + lo_off;
  const unsigned char* Ard_hi = As + (wm + lm) * 128 + hi_off;
  const unsigned char* Brd_lo = Bs + (wn + lm) * 128 + lo_off;
  const unsigned char* Brd_hi = Bs + (wn + lm) * 128 + hi_off;

  // b ping-pong (per-tile) + a ping-pong (per-phase)
  i32x8 bA0, bA1, bA2, bA3, bB0, bB1, bB2, bB3;
  i32x8 ax0, ax1, ay0, ay1;

#define STGA(c_, kn_, p_) \
    gload16(Ag + (kn_) + (size_t)(c_) * 64 * KTOT, AsW + (p_) * 32768 + (c_) * 8192)
#define STGB(c_, kn_, p_) \
    gload16(Bg + (kn_) + (size_t)(c_) * 64 * KTOT, BsW + (p_) * 32768 + (c_) * 8192)
#define LDA(d_, i_, P_) { \
    i32x4 lo_ = *(const i32x4*)(Ard_lo + (P_) * 32768 + (i_) * 2048); \
    i32x4 hi_ = *(const i32x4*)(Ard_hi + (P_) * 32768 + (i_) * 2048); \
    d_ = __builtin_shufflevector(lo_, hi_, 0, 1, 2, 3, 4, 5, 6, 7); }
#define LDB(d_, j_, P_) { \
    i32x4 lo_ = *(const i32x4*)(Brd_lo + (P_) * 32768 + (j_) * 2048); \
    i32x4 hi_ = *(const i32x4*)(Brd_hi + (P_) * 32768 + (j_) * 2048); \
    d_ = __builtin_shufflevector(lo_, hi_, 0, 1, 2, 3, 4, 5, 6, 7); }
#define MF(a_, b_, c_) \
    __builtin_amdgcn_mfma_scale_f32_16x16x128_f8f6f4((a_), (b_), (c_), 0, 0, 0, sa, 0, sb)
#define BARR() { asm volatile("" ::: "memory"); __builtin_amdgcn_s_barrier(); \
                 asm volatile("" ::: "memory"); }
#define VM(n_) asm volatile("s_waitcnt vmcnt(" #n_ ")" ::: "memory")
#define SCHED0() __builtin_amdgcn_sched_barrier(0)
#define MM8(i0_, i1_, aA_, aB_, B0_, B1_, B2_, B3_) { \
    __builtin_amdgcn_s_setprio(1); \
    acc[i0_][0] = MF(aA_, B0_, acc[i0_][0]); \
    acc[i0_][1] = MF(aA_, B1_, acc[i0_][1]); \
    acc[i0_][2] = MF(aA_, B2_, acc[i0_][2]); \
    acc[i0_][3] = MF(aA_, B3_, acc[i0_][3]); \
    acc[i1_][0] = MF(aB_, B0_, acc[i1_][0]); \
    acc[i1_][1] = MF(aB_, B1_, acc[i1_][1]); \
    acc[i1_][2] = MF(aB_, B2_, acc[i1_][2]); \
    acc[i1_][3] = MF(aB_, B3_, acc[i1_][3]); \
    __builtin_amdgcn_s_setprio(0); }

// One 128-K tile. P_ = read-buffer parity (compile-time), BC* = this tile's
// b-frags (loaded at prev ph3), BN* = next tile's b-frags (loaded this ph3),
// kn_ = K offset staged for tile t+1, LAST_ = tail tile (no stage/preload).
#define TILE(P_, BC0_, BC1_, BC2_, BC3_, BN0_, BN1_, BN2_, BN3_, kn_, LAST_) { \
    /* ph0: LDF f2,f3 | STG B0',B1' | MM8(f0,f1) | vmcnt | bar */ \
    LDA(ay0, 2, P_); LDA(ay1, 3, P_); \
    if (!(LAST_)) { STGB(0, kn_, 1 - (P_)); STGB(1, kn_, 1 - (P_)); } \
    SCHED0(); \
    MM8(0, 1, ax0, ax1, BC0_, BC1_, BC2_, BC3_); \
    if (LAST_) { VM(0); } else { VM(2); }  /* A1,A3 of this tile landed */ \
    BARR(); \
    /* ph1: LDF f4,f5 | STG B2',B3',A0',A2' | MM8(f2,f3) | bar */ \
    LDA(ax0, 4, P_); LDA(ax1, 5, P_); \
    if (!(LAST_)) { STGB(2, kn_, 1 - (P_)); STGB(3, kn_, 1 - (P_)); \
                    STGA(0, kn_, 1 - (P_)); STGA(2, kn_, 1 - (P_)); } \
    SCHED0(); \
    MM8(2, 3, ay0, ay1, BC0_, BC1_, BC2_, BC3_); \
    BARR(); \
    /* ph2: LDF f6,f7 | STG A1',A3' | MM8(f4,f5) | vmcnt | bar */ \
    LDA(ay0, 6, P_); LDA(ay1, 7, P_); \
    if (!(LAST_)) { STGA(1, kn_, 1 - (P_)); STGA(3, kn_, 1 - (P_)); } \
    SCHED0(); \
    MM8(4, 5, ax0, ax1, BC0_, BC1_, BC2_, BC3_); \
    if (!(LAST_)) { VM(2); }  /* B0'..B3',A0',A2' landed; A1',A3' in flight */ \
    BARR(); \
    /* ph3: preload next tile's b0-3 + f0,f1 from back buffer | MM8(f6,f7) */ \
    if (!(LAST_)) { \
      LDB(BN0_, 0, 1 - (P_)); LDB(BN1_, 1, 1 - (P_)); \
      LDB(BN2_, 2, 1 - (P_)); LDB(BN3_, 3, 1 - (P_)); \
      LDA(ax0, 0, 1 - (P_)); LDA(ax1, 1, 1 - (P_)); \
    } \
    SCHED0(); \
    MM8(6, 7, ay0, ay1, BC0_, BC1_, BC2_, BC3_); \
    if (!(LAST_)) { BARR(); } \
  }

  // Prologue: stage tile 0 (FIFO: B0..B3,A0,A2 then A1,A3), then preload
  // tile 0's b-frags + first a-pair.
  STGB(0, 0, 0); STGB(1, 0, 0); STGB(2, 0, 0); STGB(3, 0, 0);
  STGA(0, 0, 0); STGA(2, 0, 0);
  STGA(1, 0, 0); STGA(3, 0, 0);
  VM(2);
  BARR();
  LDB(bA0, 0, 0); LDB(bA1, 1, 0); LDB(bA2, 2, 0); LDB(bA3, 3, 0);
  LDA(ax0, 0, 0); LDA(ax1, 1, 0);

  const int NT = KTOT / 128;
  for (int t = 0; t < NT - 2; t += 2) {
    TILE(0, bA0, bA1, bA2, bA3, bB0, bB1, bB2, bB3, (t + 1) * 128, false);
    TILE(1, bB0, bB1, bB2, bB3, bA0, bA1, bA2, bA3, (t + 2) * 128, false);
  }
  TILE(0, bA0, bA1, bA2, bA3, bB0, bB1, bB2, bB3, (NT - 1) * 128, false);
  TILE(1, bB0, bB1, bB2, bB3, bA0, bA1, bA2, bA3, 0, true);

#undef STGA
#undef STGB
#undef LDA
#undef LDB
#undef MF
#undef BARR
#undef VM
#undef SCHED0
#undef MM8
#undef TILE
}

// ---- GEMM1: Z = X @ W1, epilogue Dh = 64*(tanh(z)-tanh(z+s*w3)) -> fp8 ----
// 1024 blocks (64 m x 16 n), 512 thr, 1 block/CU, 4 exact generations.
// XCD map: x = l&7 owns m-panels x*8..x*8+7 forever (2 MB Xb L2-pinned);
// n advances across generations (1 MB W1T slice live per gen).
__global__ __launch_bounds__(512, 2) void gemm1_dh(
    const unsigned char* __restrict__ Xb,    // B_N x D_N fp8 (x1)
    const unsigned char* __restrict__ W1T,   // H_N x D_N fp8 (x16)
    const float* __restrict__ b1,
    const float* __restrict__ w3,            // H_N : W1[pci][h] f32
    const float* __restrict__ s,             // B_N : 1-2*col
    unsigned int* __restrict__ Dh4) {        // B_N x H_N fp8 (x64), perm'd cols
  __shared__ alignas(16) unsigned char As[65536];
  __shared__ alignas(16) unsigned char Bs[65536];
  const int l = blockIdx.x;
  const int x = l & 7;
  const int k = l >> 3;                      // 0..127 per XCD
  const int m0 = (x * 8 + (k & 7)) * 256;
  const int n0 = (k >> 3) * 256;

  f32x4 acc[8][4] = {};
  mx8_mainloop<D_N>(Xb, W1T, m0, n0, 127, 123, As, Bs, acc);  // 2^0 * 2^-4

  const int tid = threadIdx.x;
  const int lane = tid & 63;
  const int wave = tid >> 6;
  const int wm = (wave >> 2) * 128;
  const int wn = (wave & 3) * 64;
  const int lm = lane & 15;
  const int quad = lane >> 4;

  float ewp[4], ewm[4], nump[4], numm[4], b1v[4];
#pragma unroll
  for (int j = 0; j < 4; j++) {
    int gh = n0 + wn + j * 16 + lm;
    float w = w3[gh];
    float ep = __expf(2.0f * w);
    float em = __expf(-2.0f * w);
    ewp[j] = ep; ewm[j] = em;
    nump[j] = 128.0f * (1.0f - ep);
    numm[j] = 128.0f * (1.0f - em);
    b1v[j] = b1[gh];
  }
  const size_t coloff = (size_t)((n0 + wn) >> 2) + lm;
#pragma unroll
  for (int i = 0; i < 8; i++) {
#pragma unroll
    for (int r = 0; r < 4; r++) {
      int gb = m0 + wm + i * 16 + quad * 4 + r;
      bool sp = s[gb] > 0.0f;
      float o[4];
#pragma unroll
      for (int j = 0; j < 4; j++) {
        float ews = sp ? ewp[j] : ewm[j];
        float num = sp ? nump[j] : numm[j];
        float z = fminf(acc[i][j][r] + b1v[j], 12.0f);
        float E = __expf(2.0f * z);
        float den = (E * ews + 1.0f) * (E + 1.0f);
        o[j] = (E * num) * __builtin_amdgcn_rcpf(den);  // 64*dh
      }
      int p = __builtin_amdgcn_cvt_pk_fp8_f32(o[0], o[1], 0, false);
      p = __builtin_amdgcn_cvt_pk_fp8_f32(o[2], o[3], p, true);
      Dh4[(size_t)gb * (H_N / 4) + coloff] = (unsigned int)p;
    }
  }
}

// ---- GEMM2: Y = Dh @ W2, epilogue mean-scaled sum|Y| -> atomic d_out ----
// 256 blocks (64 m x 4 n) = ONE exact generation at 1 block/CU; same
// m-panel<->XCD map as gemm1 so Dh re-reads hit that XCD's L2.
__global__ __launch_bounds__(512, 2) void gemm2_abs(
    const unsigned char* __restrict__ Dh,    // B_N x H_N fp8 (x64), perm'd K
    const unsigned char* __restrict__ W2T,   // D_N x H_N fp8 (x64), perm'd K
    float* __restrict__ out) {
  __shared__ alignas(16) unsigned char As[65536];
  __shared__ alignas(16) unsigned char Bs[65536];
  __shared__ float wsum[8];
  const int l = blockIdx.x;
  const int x = l & 7;
  const int k = l >> 3;                      // 0..31 per XCD
  const int m0 = (x * 8 + (k & 7)) * 256;
  const int n0 = (k >> 3) * 256;

  f32x4 acc[8][4] = {};
  mx8_mainloop<H_N>(Dh, W2T, m0, n0, 121, 121, As, Bs, acc);  // 2^-6 * 2^-6

  const int tid = threadIdx.x;
  const int lane = tid & 63;
  const int wave = tid >> 6;

  float t = 0.0f;
#pragma unroll
  for (int i = 0; i < 8; i++)
#pragma unroll
    for (int j = 0; j < 4; j++)
#pragma unroll
      for (int r = 0; r < 4; r++)
        t += fabsf(acc[i][j][r]);

#pragma unroll
  for (int off2 = 32; off2 > 0; off2 >>= 1)
    t += __shfl_down(t, off2, 64);
  if (lane == 0) wsum[wave] = t;
  __syncthreads();
  if (tid == 0) {
    float tt = 0.0f;
#pragma unroll
    for (int w = 0; w < 8; w++) tt += wsum[w];
    atomicAdd(out, tt * (1.0f / (float)B_N));
  }
}

extern "C" void kernel_launch(void* const* d_in, const int* in_sizes, int n_in,
                              void* d_out, int out_size, void* d_ws, size_t ws_size,
                              hipStream_t stream) {
  const float* X  = (const float*)d_in[0];
  const float* W1 = (const float*)d_in[1];
  const float* b1 = (const float*)d_in[2];
  const float* W2 = (const float*)d_in[3];
  // d_in[4] = b2 : cancels in the difference
  const int* pci  = (const int*)d_in[5];

  char* ws = (char*)d_ws;
  size_t off = 0;
  unsigned char* Xb  = (unsigned char*)(ws + off); off += (size_t)B_N * D_N;
  unsigned char* W1T = (unsigned char*)(ws + off); off += (size_t)H_N * D_N;
  unsigned char* W2T = (unsigned char*)(ws + off); off += (size_t)D_N * H_N;
  float* w3  = (float*)(ws + off); off += (size_t)H_N * 4;
  float* s   = (float*)(ws + off); off += (size_t)B_N * 4;
  unsigned char* Dh  = (unsigned char*)(ws + off); off += (size_t)B_N * H_N;
  if (ws_size < off) return;

  prep_kernel<<<16384, 256, 0, stream>>>((const float4*)X, (int*)Xb, s,
                                         W1, W1T, w3, W2, W2T, pci,
                                         (float*)d_out);
  gemm1_dh<<<1024, 512, 0, stream>>>(Xb, W1T, b1, w3, s, (unsigned int*)Dh);
  gemm2_abs<<<256, 512, 0, stream>>>(Dh, W2T, (float*)d_out);
}